// Round 21
// baseline (1152.660 us; speedup 1.0000x reference)
//
#include <hip/hip_runtime.h>
#include <hip/hip_bf16.h>

#define N_ROWS 131072
#define DIM    768
#define K_C    2000
#define K_PAD  2048
#define TAU    0.2f
#define LISTCAP 8192

typedef _Float16 f16;
typedef _Float16 f16x4 __attribute__((ext_vector_type(4)));
typedef _Float16 f16x8 __attribute__((ext_vector_type(8)));
typedef float    f32x4 __attribute__((ext_vector_type(4)));

// ---- workspace layout (bytes) ----
#define OFF_CN   6291456    // cn   [2048] f32
#define OFF_XN   6299648    // xn   [131072] f32
#define OFF_PMIN 6823936    // pmin [16][131072] f32
#define OFF_PSEC 15212544   // psec [16][131072] f32
#define OFF_PIDX 23601152   // pidx [16][131072] i32
#define OFF_CNT  31989760   // counter
#define OFF_LIST 31990016   // list [8192] i32
#define OFF_CN64 32022784   // cn64 [2048] f64
#define OFF_XH   32039168   // xh [131072][768] f16

static __device__ __forceinline__ void gload16(const void* g, void* l) {
  __builtin_amdgcn_global_load_lds(
      (const __attribute__((address_space(1))) unsigned int*)g,
      (__attribute__((address_space(3))) unsigned int*)l, 16, 0, 0);
}

// K1a: c_norm, 64 blocks x 8-way d-split (fp32 feeds gate margins only;
// fp64 cn64 for the exact recheck).
__global__ __launch_bounds__(256) void prep_cn(const float* __restrict__ cent,
                                               float* __restrict__ cn,
                                               double* __restrict__ cn64) {
#pragma clang fp contract(off)
  __shared__ float pf[8][32];
  __shared__ double pd[8][32];
  int t = threadIdx.x;
  int kk = t & 31;
  int k = blockIdx.x * 32 + kk;
  int p = t >> 5;
  float s = 0.0f;
  double s64 = 0.0;
  for (int d = p * 96; d < p * 96 + 96; ++d) {
    float c = (k < K_C) ? cent[d * K_C + k] : 0.0f;
    float sq = c * c;
    s = s + sq;
    s64 += (double)c * (double)c;
  }
  pf[p][kk] = s;
  pd[p][kk] = s64;
  __syncthreads();
  if (p == 0) {
    float ss = 0.0f;
    double ss64 = 0.0;
#pragma unroll
    for (int q = 0; q < 8; ++q) {
      ss = ss + pf[q][kk];
      ss64 += pd[q][kk];
    }
    cn[k] = (k < K_C) ? ss : INFINITY;
    cn64[k] = (k < K_C) ? ss64 : (double)INFINITY;
  }
}

// K1b: centroid transpose to f16 via 64x64 LDS tile.
__global__ __launch_bounds__(256) void prep_ct(const float* __restrict__ cent,
                                               f16* __restrict__ cTh) {
  __shared__ float ld[64][65];
  int k0 = blockIdx.x * 64;  // 32 blocks
  int d0 = blockIdx.y * 64;  // 12 blocks
  int tid = threadIdx.x;
#pragma unroll
  for (int it = 0; it < 16; ++it) {
    int idx = it * 256 + tid;
    int dd = idx >> 6, kk = idx & 63;
    int k = k0 + kk;
    ld[dd][kk] = (k < K_C) ? cent[(size_t)(d0 + dd) * K_C + k] : 0.0f;
  }
  __syncthreads();
#pragma unroll
  for (int it = 0; it < 16; ++it) {
    int idx = it * 256 + tid;
    int kk = idx >> 6, dd = idx & 63;
    cTh[(size_t)(k0 + kk) * DIM + d0 + dd] = (f16)ld[dd][kk];
  }
}

// K2: x_norm (numpy FLOAT_pairwise_sum(768) scalar semantics) fused with
// x -> f16.
__global__ __launch_bounds__(256) void xnorm_prepx(const float* __restrict__ x,
                                                   float* __restrict__ xn,
                                                   f16* __restrict__ xh) {
#pragma clang fp contract(off)
  __shared__ __align__(16) float buf[16 * DIM];  // 48 KB, 16 rows
  int row0 = blockIdx.x * 16;
  int tid = threadIdx.x;
  const f32x4* src = (const f32x4*)(x + (size_t)row0 * DIM);
  f32x4* dst = (f32x4*)buf;
#pragma unroll
  for (int c = 0; c < 12; ++c) {
    f32x4 v = src[c * 256 + tid];
    dst[c * 256 + tid] = v;
    f16x4 hv;
#pragma unroll
    for (int j = 0; j < 4; ++j) hv[j] = (f16)v[j];
    *(f16x4*)(xh + (size_t)row0 * DIM + (size_t)(c * 256 + tid) * 4) = hv;
  }
  __syncthreads();
  int w = tid >> 6, lane = tid & 63;
  int b = lane >> 3, j = lane & 7;
#pragma unroll
  for (int rr = 0; rr < 4; ++rr) {
    int r = w * 4 + rr;
    const float* a = buf + r * DIM + 96 * b + j;
    float v0 = a[0];
    float acc = v0 * v0;
#pragma unroll
    for (int t = 1; t < 12; ++t) {
      float q = a[8 * t];
      float s = q * q;
      acc = acc + s;
    }
    float v = acc;
    { float o = __shfl_xor(v, 1);  v = v + o; }
    { float o = __shfl_xor(v, 2);  v = v + o; }
    { float o = __shfl_xor(v, 4);  v = v + o; }
    { float o = __shfl_xor(v, 8);  v = v + o; }
    { float o = __shfl_xor(v, 16); v = v + o; }
    { float o = __shfl_xor(v, 32); v = v + o; }
    if (lane == 0) xn[row0 + r] = v;
  }
}

// K3: f16 MFMA GEMM + fused argmin. 64x128 tile variant of the r13
// skeleton: ring slot = 12 KB (A 4K @0, B 8K @4096), slots {0,12288,
// 24576} = 36 KB -> 4 blocks/CU (16 waves; occupancy was the proven
// dominant term r11-r19). 4 waves = 2x2 of 32x64 output (6 ds_read :
// 8 MFMA). Counted vmcnt(3) (3 gload16/wave/stage), one barrier/step,
// granule swizzle verbatim (slot s at row r holds granule s^((r>>1)&3)).
#define STAGE3(bufo)                                                           \
  do {                                                                         \
    gload16(pA0, ldsb + (bufo) + w * 1024);                                    \
    gload16(pB0, ldsb + (bufo) + 4096 + w * 1024);                             \
    gload16(pB1, ldsb + (bufo) + 4096 + (w + 4) * 1024);                       \
    pA0 += 64; pB0 += 64; pB1 += 64;                                           \
  } while (0)

__global__ __launch_bounds__(256, 4) void kmeans_main(
    const f16* __restrict__ xh, const f16* __restrict__ cTh,
    const float* __restrict__ cn, const float* __restrict__ xn,
    float* __restrict__ pmin, float* __restrict__ psec,
    int* __restrict__ pidx) {
  __shared__ __align__(16) f16 lds[18432];  // 36 KiB: 3 x 12 KB slots
  char* ldsb = (char*)lds;

  int d0 = blockIdx.x;
  int g  = (d0 & 7) * 4096 + (d0 >> 3);  // XCD-grouped, 32768 blocks
  int pb = g & 15;   // column panel (128 cols)
  int rb = g >> 4;   // row block (64 rows), 0..2047

  int tid  = threadIdx.x;
  int w    = tid >> 6;
  int lane = tid & 63;
  int wrow = (w >> 1) * 32;   // 2 row-halves of 32
  int wcol = (w & 1) * 64;    // 2 col-halves of 64

  int rsel = lane & 15;
  int ksel = lane >> 4;
  int rs = (ksel ^ ((rsel >> 1) & 3)) << 4;  // swizzled granule byte-offset

  // staging: A = 4 chunks (64 rows), B = 8 chunks (128 cols); 1KB chunks
  // of 16 rows x 64 B. Wave w stages A-chunk w, B-chunks {w, w+4}.
  int grn = (lane & 3) ^ ((lane >> 3) & 3);  // inverse-swizzled src granule
  const char* pA0 = (const char*)xh +
      ((size_t)(rb * 64 + w * 16 + (lane >> 2)) * DIM + grn * 8) * 2;
  const char* pB0 = (const char*)cTh +
      ((size_t)(pb * 128 + w * 16 + (lane >> 2)) * DIM + grn * 8) * 2;
  const char* pB1 = (const char*)cTh +
      ((size_t)(pb * 128 + (w + 4) * 16 + (lane >> 2)) * DIM + grn * 8) * 2;

  f32x4 acc[2][4] = {};

  STAGE3(0);
  STAGE3(12288);

  int cb = 0;       // current slot offset
  int sb = 24576;   // stage target (slot of kt+2)
#pragma unroll 3
  for (int kt = 0; kt < 24; ++kt) {
    if (kt < 23) {
      asm volatile("s_waitcnt vmcnt(3)" ::: "memory");  // tile kt landed;
                                                        // kt+1 stays in flight
    } else {
      asm volatile("s_waitcnt vmcnt(0)" ::: "memory");
    }
    __builtin_amdgcn_sched_barrier(0);
    __builtin_amdgcn_s_barrier();
    __builtin_amdgcn_sched_barrier(0);

    if (kt < 22) STAGE3(sb);  // into slot freed at kt-1

    f16x8 ah[2], bh[4];
    int abase = cb + (wrow + rsel) * 64 + rs;
    int bbase = cb + 4096 + (wcol + rsel) * 64 + rs;
#pragma unroll
    for (int m = 0; m < 2; ++m) ah[m] = *(const f16x8*)(ldsb + abase + m * 1024);
#pragma unroll
    for (int n = 0; n < 4; ++n) bh[n] = *(const f16x8*)(ldsb + bbase + n * 1024);

    // compiler interleaves ds_read completion with MFMA via lgkmcnt(N)
    __builtin_amdgcn_s_setprio(1);
#pragma unroll
    for (int m = 0; m < 2; ++m)
#pragma unroll
      for (int n = 0; n < 4; ++n)
        acc[m][n] = __builtin_amdgcn_mfma_f32_16x16x32_f16(ah[m], bh[n],
                                                           acc[m][n], 0, 0, 0);
    __builtin_amdgcn_s_setprio(0);

    cb = (cb == 24576) ? 0 : cb + 12288;
    sb = (sb == 24576) ? 0 : sb + 12288;
  }

  __syncthreads();  // drain; LDS reused below
  float* lv = (float*)lds;                 // [2][64]
  float* lsv = (float*)lds + 128;          // [2][64]
  int*   li = (int*)((float*)lds + 256);   // [2][64]

  int colbase = pb * 128 + wcol + rsel;
  float cnv[4];
#pragma unroll
  for (int n = 0; n < 4; ++n) cnv[n] = cn[colbase + n * 16];
  int g4 = ksel * 4;

#pragma unroll
  for (int m = 0; m < 2; ++m) {
#pragma unroll
    for (int j = 0; j < 4; ++j) {
      int trow = wrow + m * 16 + g4 + j;   // 0..63
      float xv = xn[rb * 64 + trow];
      float v1 = 0.0f, v2 = INFINITY;
      int i1 = 0;
#pragma unroll
      for (int n = 0; n < 4; ++n) {
        float dd = (xv - 2.0f * acc[m][n][j]) + cnv[n];
        int ci = colbase + n * 16;
        if (n == 0) { v1 = dd; i1 = ci; }
        else if (dd < v1) { v2 = v1; v1 = dd; i1 = ci; }
        else { v2 = fminf(v2, dd); }
      }
#pragma unroll
      for (int off = 1; off < 16; off <<= 1) {
        float ov1 = __shfl_xor(v1, off);
        float ov2 = __shfl_xor(v2, off);
        int oi1 = __shfl_xor(i1, off);
        if (ov1 < v1 || (ov1 == v1 && oi1 < i1)) {
          v2 = fminf(v1, ov2); v1 = ov1; i1 = oi1;
        } else {
          v2 = fminf(v2, ov1);
        }
      }
      if ((lane & 15) == 0) {
        lv[(w & 1) * 64 + trow] = v1;
        lsv[(w & 1) * 64 + trow] = v2;
        li[(w & 1) * 64 + trow] = i1;
      }
    }
  }
  __syncthreads();
  if (tid < 64) {
    float a1 = lv[tid], a2 = lsv[tid];
    int aj = li[tid];
    float b1 = lv[64 + tid], b2 = lsv[64 + tid];
    int bj = li[64 + tid];
    float v1, v2; int i1;
    if (b1 < a1 || (b1 == a1 && bj < aj)) { v1 = b1; i1 = bj; v2 = fminf(b2, a1); }
    else { v1 = a1; i1 = aj; v2 = fminf(a2, b1); }
    size_t o = (size_t)pb * N_ROWS + rb * 64 + tid;
    pmin[o] = v1;
    psec[o] = v2;
    pidx[o] = i1;
  }
}

// K4: merge 16 panel triples; flag ambiguous rows (margin < TAU).
__global__ void merge_detect(const float* __restrict__ pmin,
                             const float* __restrict__ psec,
                             const int* __restrict__ pidx, int* __restrict__ out,
                             int* __restrict__ list, int* __restrict__ counter) {
  int n = blockIdx.x * 256 + threadIdx.x;
  float v1 = INFINITY, v2 = INFINITY;
  int i1 = 0x7fffffff;
  for (int p = 0; p < 16; ++p) {
    float a1 = pmin[(size_t)p * N_ROWS + n];
    float a2 = psec[(size_t)p * N_ROWS + n];
    int aj = pidx[(size_t)p * N_ROWS + n];
    if (a1 < v1 || (a1 == v1 && aj < i1)) {
      v2 = fminf(v1, a2); v1 = a1; i1 = aj;
    } else {
      v2 = fminf(v2, a1);
    }
  }
  out[n] = i1;
  if (v2 - v1 < TAU) {
    int idx = atomicAdd(counter, 1);
    if (idx < LISTCAP) list[idx] = n;
  }
}

// K5: float64 exact recheck, BATCH-2 (r17 proven: load-balance-bound).
// 16 NAMED f64 accumulators (rule #20).
#define ACCS(R) \
  double a##R##0 = 0, a##R##1 = 0, a##R##2 = 0, a##R##3 = 0, \
         a##R##4 = 0, a##R##5 = 0, a##R##6 = 0, a##R##7 = 0
#define FMAS(R, XV) \
  a##R##0 = fma(XV, c0, a##R##0); a##R##1 = fma(XV, c1, a##R##1); \
  a##R##2 = fma(XV, c2, a##R##2); a##R##3 = fma(XV, c3, a##R##3); \
  a##R##4 = fma(XV, c4, a##R##4); a##R##5 = fma(XV, c5, a##R##5); \
  a##R##6 = fma(XV, c6, a##R##6); a##R##7 = fma(XV, c7, a##R##7)
#define EVAL(R)                                                         \
  {                                                                     \
    double dots[8] = {a##R##0, a##R##1, a##R##2, a##R##3,               \
                      a##R##4, a##R##5, a##R##6, a##R##7};              \
    double bv = (double)INFINITY;                                       \
    int bi = 0x7fffffff;                                                \
    _Pragma("unroll") for (int j = 0; j < 8; ++j) {                     \
      int k = tid + j * 256;                                            \
      if (k < K_C) {                                                    \
        double dd = (xnorms[R] - 2.0 * dots[j]) + cn64[k];              \
        if (dd < bv) { bv = dd; bi = k; }                               \
      }                                                                 \
    }                                                                   \
    rv[tid] = bv; ri[tid] = bi;                                         \
    __syncthreads();                                                    \
    for (int s = 128; s > 0; s >>= 1) {                                 \
      if (tid < s) {                                                    \
        double ov = rv[tid + s];                                        \
        int oi = ri[tid + s];                                           \
        if (ov < rv[tid] || (ov == rv[tid] && oi < ri[tid])) {          \
          rv[tid] = ov; ri[tid] = oi;                                   \
        }                                                               \
      }                                                                 \
      __syncthreads();                                                  \
    }                                                                   \
    if (tid == 0 && (R) < nrows) out[list[b0 + (R)]] = ri[0];           \
    __syncthreads();                                                    \
  }

__global__ __launch_bounds__(256) void exact_recheck64(
    const float* __restrict__ x, const float* __restrict__ cent,
    const double* __restrict__ cn64, const int* __restrict__ list,
    const int* __restrict__ counter, int* __restrict__ out) {
  __shared__ __align__(16) float xrow[2][DIM];  // 6 KB
  __shared__ double rv[256];
  __shared__ int ri[256];
  __shared__ double xnorms[2];
  int cnt = counter[0];
  if (cnt > LISTCAP) cnt = LISTCAP;
  int b0 = blockIdx.x * 2;
  if (b0 >= cnt) return;
  int nrows = cnt - b0;
  if (nrows > 2) nrows = 2;
  int tid = threadIdx.x;
  for (int r = 0; r < 2; ++r) {
    int n = list[b0 + (r < nrows ? r : 0)];
    double part = 0.0;
    for (int d = tid; d < DIM; d += 256) {
      float v = x[(size_t)n * DIM + d];
      xrow[r][d] = v;
      part += (double)v * (double)v;
    }
    rv[tid] = part;
    __syncthreads();
    for (int s = 128; s > 0; s >>= 1) {
      if (tid < s) rv[tid] += rv[tid + s];
      __syncthreads();
    }
    if (tid == 0) xnorms[r] = rv[0];
    __syncthreads();
  }

  int k7 = tid + 1792;
  int k7c = (k7 < K_C) ? k7 : (K_C - 1);
  ACCS(0); ACCS(1);
#pragma unroll 2
  for (int d = 0; d < DIM; ++d) {
    const float* cp = cent + (size_t)d * K_C + tid;
    double c0 = cp[0], c1 = cp[256], c2 = cp[512], c3 = cp[768];
    double c4 = cp[1024], c5 = cp[1280], c6 = cp[1536];
    double c7 = cp[k7c - tid];
    double x0 = xrow[0][d], x1 = xrow[1][d];
    FMAS(0, x0); FMAS(1, x1);
  }
  EVAL(0) EVAL(1)
}

extern "C" void kernel_launch(void* const* d_in, const int* in_sizes, int n_in,
                              void* d_out, int out_size, void* d_ws, size_t ws_size,
                              hipStream_t stream) {
  const float* x = (const float*)d_in[0];
  const float* cent = (const float*)d_in[1];
  char* ws = (char*)d_ws;
  f16* cTh = (f16*)ws;
  float* cn = (float*)(ws + OFF_CN);
  float* xn = (float*)(ws + OFF_XN);
  float* pmin = (float*)(ws + OFF_PMIN);
  float* psec = (float*)(ws + OFF_PSEC);
  int* pidx = (int*)(ws + OFF_PIDX);
  int* counter = (int*)(ws + OFF_CNT);
  int* list = (int*)(ws + OFF_LIST);
  double* cn64 = (double*)(ws + OFF_CN64);
  f16* xh = (f16*)(ws + OFF_XH);

  hipMemsetAsync(counter, 0, 4, stream);
  prep_cn<<<64, 256, 0, stream>>>(cent, cn, cn64);
  prep_ct<<<dim3(32, 12), 256, 0, stream>>>(cent, cTh);
  xnorm_prepx<<<N_ROWS / 16, 256, 0, stream>>>(x, xn, xh);
  kmeans_main<<<32768, 256, 0, stream>>>(xh, cTh, cn, xn, pmin, psec, pidx);
  merge_detect<<<N_ROWS / 256, 256, 0, stream>>>(pmin, psec, pidx, (int*)d_out,
                                                 list, counter);
  exact_recheck64<<<LISTCAP / 2, 256, 0, stream>>>(x, cent, cn64, list, counter,
                                                   (int*)d_out);
}

// Round 22
// 1031.757 us; speedup vs baseline: 1.1172x; 1.1172x over previous
//
#include <hip/hip_runtime.h>
#include <hip/hip_bf16.h>

#define N_ROWS 131072
#define DIM    768
#define K_C    2000
#define K_PAD  2048
#define TAU    0.2f
#define LISTCAP 8192

typedef _Float16 f16;
typedef _Float16 f16x4 __attribute__((ext_vector_type(4)));
typedef _Float16 f16x8 __attribute__((ext_vector_type(8)));
typedef float    f32x4 __attribute__((ext_vector_type(4)));

// ---- workspace layout (bytes) ----
#define OFF_CN   6291456    // cn   [2048] f32
#define OFF_XN   6299648    // xn   [131072] f32
#define OFF_PMIN 6823936    // pmin [16][131072] f32
#define OFF_PSEC 15212544   // psec [16][131072] f32
#define OFF_PIDX 23601152   // pidx [16][131072] i32
#define OFF_CNT  31989760   // counter
#define OFF_LIST 31990016   // list [8192] i32
#define OFF_CN64 32022784   // cn64 [2048] f64
#define OFF_XH   32039168   // xh [131072][768] f16

static __device__ __forceinline__ void gload16(const void* g, void* l) {
  __builtin_amdgcn_global_load_lds(
      (const __attribute__((address_space(1))) unsigned int*)g,
      (__attribute__((address_space(3))) unsigned int*)l, 16, 0, 0);
}

// K1: fused centroid prep. Blocks 0..63: c_norm (fp32 for gate margins,
// fp64 for recheck). Blocks 64..447: transpose to f16 via 64x64 LDS tile.
__global__ __launch_bounds__(256) void prep_c(const float* __restrict__ cent,
                                              float* __restrict__ cn,
                                              double* __restrict__ cn64,
                                              f16* __restrict__ cTh) {
#pragma clang fp contract(off)
  __shared__ __align__(16) float ld[64][65];  // covers both phases
  int bid = blockIdx.x;
  int tid = threadIdx.x;
  if (bid < 64) {
    float* pf = (float*)ld;             // [8][32]
    double* pd = (double*)((float*)ld + 256);  // [8][32]
    int kk = tid & 31;
    int k = bid * 32 + kk;
    int p = tid >> 5;
    float s = 0.0f;
    double s64 = 0.0;
    for (int d = p * 96; d < p * 96 + 96; ++d) {
      float c = (k < K_C) ? cent[d * K_C + k] : 0.0f;
      float sq = c * c;
      s = s + sq;
      s64 += (double)c * (double)c;
    }
    pf[p * 32 + kk] = s;
    pd[p * 32 + kk] = s64;
    __syncthreads();
    if (p == 0) {
      float ss = 0.0f;
      double ss64 = 0.0;
#pragma unroll
      for (int q = 0; q < 8; ++q) {
        ss = ss + pf[q * 32 + kk];
        ss64 += pd[q * 32 + kk];
      }
      cn[k] = (k < K_C) ? ss : INFINITY;
      cn64[k] = (k < K_C) ? ss64 : (double)INFINITY;
    }
    return;
  }
  int tb = bid - 64;          // 0..383
  int k0 = (tb & 31) * 64;    // 32 col-blocks
  int d0 = (tb >> 5) * 64;    // 12 row-blocks
#pragma unroll
  for (int it = 0; it < 16; ++it) {
    int idx = it * 256 + tid;
    int dd = idx >> 6, kk = idx & 63;
    int k = k0 + kk;
    ld[dd][kk] = (k < K_C) ? cent[(size_t)(d0 + dd) * K_C + k] : 0.0f;
  }
  __syncthreads();
#pragma unroll
  for (int it = 0; it < 16; ++it) {
    int idx = it * 256 + tid;
    int kk = idx >> 6, dd = idx & 63;
    cTh[(size_t)(k0 + kk) * DIM + d0 + dd] = (f16)ld[dd][kk];
  }
}

// K2: x_norm (numpy FLOAT_pairwise_sum(768) scalar semantics) fused with
// x -> f16.
__global__ __launch_bounds__(256) void xnorm_prepx(const float* __restrict__ x,
                                                   float* __restrict__ xn,
                                                   f16* __restrict__ xh) {
#pragma clang fp contract(off)
  __shared__ __align__(16) float buf[16 * DIM];  // 48 KB, 16 rows
  int row0 = blockIdx.x * 16;
  int tid = threadIdx.x;
  const f32x4* src = (const f32x4*)(x + (size_t)row0 * DIM);
  f32x4* dst = (f32x4*)buf;
#pragma unroll
  for (int c = 0; c < 12; ++c) {
    f32x4 v = src[c * 256 + tid];
    dst[c * 256 + tid] = v;
    f16x4 hv;
#pragma unroll
    for (int j = 0; j < 4; ++j) hv[j] = (f16)v[j];
    *(f16x4*)(xh + (size_t)row0 * DIM + (size_t)(c * 256 + tid) * 4) = hv;
  }
  __syncthreads();
  int w = tid >> 6, lane = tid & 63;
  int b = lane >> 3, j = lane & 7;
#pragma unroll
  for (int rr = 0; rr < 4; ++rr) {
    int r = w * 4 + rr;
    const float* a = buf + r * DIM + 96 * b + j;
    float v0 = a[0];
    float acc = v0 * v0;
#pragma unroll
    for (int t = 1; t < 12; ++t) {
      float q = a[8 * t];
      float s = q * q;
      acc = acc + s;
    }
    float v = acc;
    { float o = __shfl_xor(v, 1);  v = v + o; }
    { float o = __shfl_xor(v, 2);  v = v + o; }
    { float o = __shfl_xor(v, 4);  v = v + o; }
    { float o = __shfl_xor(v, 8);  v = v + o; }
    { float o = __shfl_xor(v, 16); v = v + o; }
    { float o = __shfl_xor(v, 32); v = v + o; }
    if (lane == 0) xn[row0 + r] = v;
  }
}

// K3: f16 MFMA GEMM + fused argmin — r13 PROVEN BEST (661-682us across
// four reproductions; MfmaUtil ~28%, conflicts 0). Triple-buffered BK=32,
// one barrier per step, counted vmcnt(4), granule swizzle (slot s at row r
// holds granule s^((r>>1)&3)), hoisted stage pointers, 48KB -> 3 blocks/CU.
// setprio REMOVED this round (m190: setprio negative on single-phase
// lockstep GEMM; only pays with phase-split schedules).
// Tile sweep record: 64x128=748, 128x128=661, 128x256=745, 256x256=743.
#define STAGE3(bufo)                                                           \
  do {                                                                         \
    gload16(pA0, ldsb + (bufo) + c0 * 1024);                                   \
    gload16(pA1, ldsb + (bufo) + c1 * 1024);                                   \
    gload16(pB0, ldsb + 24576 + (bufo) + c0 * 1024);                           \
    gload16(pB1, ldsb + 24576 + (bufo) + c1 * 1024);                           \
    pA0 += 64; pA1 += 64; pB0 += 64; pB1 += 64;                                \
  } while (0)

__global__ __launch_bounds__(256, 3) void kmeans_main(
    const f16* __restrict__ xh, const f16* __restrict__ cTh,
    const float* __restrict__ cn, const float* __restrict__ xn,
    float* __restrict__ pmin, float* __restrict__ psec,
    int* __restrict__ pidx) {
  __shared__ __align__(16) f16 lds[24576];  // 48 KiB
  char* ldsb = (char*)lds;

  int d0 = blockIdx.x;
  int g  = (d0 & 7) * 2048 + (d0 >> 3);  // XCD-grouped
  int pb = g & 15;
  int rb = g >> 4;

  int tid  = threadIdx.x;
  int w    = tid >> 6;
  int lane = tid & 63;
  int wrow = (w >> 1) * 64;
  int wcol = (w & 1) * 64;

  int rsel = lane & 15;
  int ksel = lane >> 4;
  int rs = (ksel ^ ((rsel >> 1) & 3)) << 4;  // swizzled granule byte-offset

  // staging constants: chunk = 1 KB = 16 rows x 64 B; this wave's chunks
  int c0 = w * 2, c1 = w * 2 + 1;
  int grn = (lane & 3) ^ ((lane >> 3) & 3);  // inverse-swizzled src granule
  const char* pA0 = (const char*)xh +
      ((size_t)(rb * 128 + c0 * 16 + (lane >> 2)) * DIM + grn * 8) * 2;
  const char* pA1 = (const char*)xh +
      ((size_t)(rb * 128 + c1 * 16 + (lane >> 2)) * DIM + grn * 8) * 2;
  const char* pB0 = (const char*)cTh +
      ((size_t)(pb * 128 + c0 * 16 + (lane >> 2)) * DIM + grn * 8) * 2;
  const char* pB1 = (const char*)cTh +
      ((size_t)(pb * 128 + c1 * 16 + (lane >> 2)) * DIM + grn * 8) * 2;

  f32x4 acc[4][4] = {};

  STAGE3(0);
  STAGE3(8192);

  int cb = 0;       // current buffer offset
  int sb = 16384;   // stage target (buffer of kt+2)
#pragma unroll 3
  for (int kt = 0; kt < 24; ++kt) {
    if (kt < 23) {
      asm volatile("s_waitcnt vmcnt(4)" ::: "memory");  // tile kt landed;
                                                        // kt+1 stays in flight
    } else {
      asm volatile("s_waitcnt vmcnt(0)" ::: "memory");
    }
    __builtin_amdgcn_sched_barrier(0);
    __builtin_amdgcn_s_barrier();
    __builtin_amdgcn_sched_barrier(0);

    if (kt < 22) STAGE3(sb);  // into buffer freed at kt-1

    f16x8 ah[4], bh[4];
    int abase = cb + (wrow + rsel) * 64 + rs;
    int bbase = cb + 24576 + (wcol + rsel) * 64 + rs;
#pragma unroll
    for (int m = 0; m < 4; ++m) ah[m] = *(const f16x8*)(ldsb + abase + m * 1024);
#pragma unroll
    for (int n = 0; n < 4; ++n) bh[n] = *(const f16x8*)(ldsb + bbase + n * 1024);

    // no manual lgkmcnt wall: compiler interleaves ds_read completion
    // with the MFMA chain via fine-grained lgkmcnt(N)
#pragma unroll
    for (int m = 0; m < 4; ++m)
#pragma unroll
      for (int n = 0; n < 4; ++n)
        acc[m][n] = __builtin_amdgcn_mfma_f32_16x16x32_f16(ah[m], bh[n],
                                                           acc[m][n], 0, 0, 0);

    cb = (cb == 16384) ? 0 : cb + 8192;
    sb = (sb == 16384) ? 0 : sb + 8192;
  }

  __syncthreads();  // drain; LDS reused below
  float* lv = (float*)lds;                 // [2][128]
  float* lsv = (float*)lds + 256;          // [2][128]
  int*   li = (int*)((float*)lds + 512);   // [2][128]

  int colbase = pb * 128 + wcol + rsel;
  float cnv[4];
#pragma unroll
  for (int n = 0; n < 4; ++n) cnv[n] = cn[colbase + n * 16];
  int g4 = ksel * 4;

#pragma unroll
  for (int m = 0; m < 4; ++m) {
#pragma unroll
    for (int j = 0; j < 4; ++j) {
      int trow = wrow + m * 16 + g4 + j;
      float xv = xn[rb * 128 + trow];
      float v1 = 0.0f, v2 = INFINITY;
      int i1 = 0;
#pragma unroll
      for (int n = 0; n < 4; ++n) {
        float dd = (xv - 2.0f * acc[m][n][j]) + cnv[n];
        int ci = colbase + n * 16;
        if (n == 0) { v1 = dd; i1 = ci; }
        else if (dd < v1) { v2 = v1; v1 = dd; i1 = ci; }
        else { v2 = fminf(v2, dd); }
      }
#pragma unroll
      for (int off = 1; off < 16; off <<= 1) {
        float ov1 = __shfl_xor(v1, off);
        float ov2 = __shfl_xor(v2, off);
        int oi1 = __shfl_xor(i1, off);
        if (ov1 < v1 || (ov1 == v1 && oi1 < i1)) {
          v2 = fminf(v1, ov2); v1 = ov1; i1 = oi1;
        } else {
          v2 = fminf(v2, ov1);
        }
      }
      if ((lane & 15) == 0) {
        lv[(w & 1) * 128 + trow] = v1;
        lsv[(w & 1) * 128 + trow] = v2;
        li[(w & 1) * 128 + trow] = i1;
      }
    }
  }
  __syncthreads();
  if (tid < 128) {
    float a1 = lv[tid], a2 = lsv[tid];
    int aj = li[tid];
    float b1 = lv[128 + tid], b2 = lsv[128 + tid];
    int bj = li[128 + tid];
    float v1, v2; int i1;
    if (b1 < a1 || (b1 == a1 && bj < aj)) { v1 = b1; i1 = bj; v2 = fminf(b2, a1); }
    else { v1 = a1; i1 = aj; v2 = fminf(a2, b1); }
    size_t o = (size_t)pb * N_ROWS + rb * 128 + tid;
    pmin[o] = v1;
    psec[o] = v2;
    pidx[o] = i1;
  }
}

// K4: merge 16 panel triples; flag ambiguous rows (margin < TAU).
__global__ void merge_detect(const float* __restrict__ pmin,
                             const float* __restrict__ psec,
                             const int* __restrict__ pidx, int* __restrict__ out,
                             int* __restrict__ list, int* __restrict__ counter) {
  int n = blockIdx.x * 256 + threadIdx.x;
  float v1 = INFINITY, v2 = INFINITY;
  int i1 = 0x7fffffff;
  for (int p = 0; p < 16; ++p) {
    float a1 = pmin[(size_t)p * N_ROWS + n];
    float a2 = psec[(size_t)p * N_ROWS + n];
    int aj = pidx[(size_t)p * N_ROWS + n];
    if (a1 < v1 || (a1 == v1 && aj < i1)) {
      v2 = fminf(v1, a2); v1 = a1; i1 = aj;
    } else {
      v2 = fminf(v2, a1);
    }
  }
  out[n] = i1;
  if (v2 - v1 < TAU) {
    int idx = atomicAdd(counter, 1);
    if (idx < LISTCAP) list[idx] = n;
  }
}

// K5: float64 exact recheck, BATCH-2 (r17 proven: load-balance-bound —
// batch-8 regressed, batch-2 best). 16 NAMED f64 accumulators (rule #20).
#define ACCS(R) \
  double a##R##0 = 0, a##R##1 = 0, a##R##2 = 0, a##R##3 = 0, \
         a##R##4 = 0, a##R##5 = 0, a##R##6 = 0, a##R##7 = 0
#define FMAS(R, XV) \
  a##R##0 = fma(XV, c0, a##R##0); a##R##1 = fma(XV, c1, a##R##1); \
  a##R##2 = fma(XV, c2, a##R##2); a##R##3 = fma(XV, c3, a##R##3); \
  a##R##4 = fma(XV, c4, a##R##4); a##R##5 = fma(XV, c5, a##R##5); \
  a##R##6 = fma(XV, c6, a##R##6); a##R##7 = fma(XV, c7, a##R##7)
#define EVAL(R)                                                         \
  {                                                                     \
    double dots[8] = {a##R##0, a##R##1, a##R##2, a##R##3,               \
                      a##R##4, a##R##5, a##R##6, a##R##7};              \
    double bv = (double)INFINITY;                                       \
    int bi = 0x7fffffff;                                                \
    _Pragma("unroll") for (int j = 0; j < 8; ++j) {                     \
      int k = tid + j * 256;                                            \
      if (k < K_C) {                                                    \
        double dd = (xnorms[R] - 2.0 * dots[j]) + cn64[k];              \
        if (dd < bv) { bv = dd; bi = k; }                               \
      }                                                                 \
    }                                                                   \
    rv[tid] = bv; ri[tid] = bi;                                         \
    __syncthreads();                                                    \
    for (int s = 128; s > 0; s >>= 1) {                                 \
      if (tid < s) {                                                    \
        double ov = rv[tid + s];                                        \
        int oi = ri[tid + s];                                           \
        if (ov < rv[tid] || (ov == rv[tid] && oi < ri[tid])) {          \
          rv[tid] = ov; ri[tid] = oi;                                   \
        }                                                               \
      }                                                                 \
      __syncthreads();                                                  \
    }                                                                   \
    if (tid == 0 && (R) < nrows) out[list[b0 + (R)]] = ri[0];           \
    __syncthreads();                                                    \
  }

__global__ __launch_bounds__(256) void exact_recheck64(
    const float* __restrict__ x, const float* __restrict__ cent,
    const double* __restrict__ cn64, const int* __restrict__ list,
    const int* __restrict__ counter, int* __restrict__ out) {
  __shared__ __align__(16) float xrow[2][DIM];  // 6 KB
  __shared__ double rv[256];
  __shared__ int ri[256];
  __shared__ double xnorms[2];
  int cnt = counter[0];
  if (cnt > LISTCAP) cnt = LISTCAP;
  int b0 = blockIdx.x * 2;
  if (b0 >= cnt) return;
  int nrows = cnt - b0;
  if (nrows > 2) nrows = 2;
  int tid = threadIdx.x;
  for (int r = 0; r < 2; ++r) {
    int n = list[b0 + (r < nrows ? r : 0)];
    double part = 0.0;
    for (int d = tid; d < DIM; d += 256) {
      float v = x[(size_t)n * DIM + d];
      xrow[r][d] = v;
      part += (double)v * (double)v;
    }
    rv[tid] = part;
    __syncthreads();
    for (int s = 128; s > 0; s >>= 1) {
      if (tid < s) rv[tid] += rv[tid + s];
      __syncthreads();
    }
    if (tid == 0) xnorms[r] = rv[0];
    __syncthreads();
  }

  int k7 = tid + 1792;
  int k7c = (k7 < K_C) ? k7 : (K_C - 1);
  ACCS(0); ACCS(1);
#pragma unroll 2
  for (int d = 0; d < DIM; ++d) {
    const float* cp = cent + (size_t)d * K_C + tid;
    double c0 = cp[0], c1 = cp[256], c2 = cp[512], c3 = cp[768];
    double c4 = cp[1024], c5 = cp[1280], c6 = cp[1536];
    double c7 = cp[k7c - tid];
    double x0 = xrow[0][d], x1 = xrow[1][d];
    FMAS(0, x0); FMAS(1, x1);
  }
  EVAL(0) EVAL(1)
}

extern "C" void kernel_launch(void* const* d_in, const int* in_sizes, int n_in,
                              void* d_out, int out_size, void* d_ws, size_t ws_size,
                              hipStream_t stream) {
  const float* x = (const float*)d_in[0];
  const float* cent = (const float*)d_in[1];
  char* ws = (char*)d_ws;
  f16* cTh = (f16*)ws;
  float* cn = (float*)(ws + OFF_CN);
  float* xn = (float*)(ws + OFF_XN);
  float* pmin = (float*)(ws + OFF_PMIN);
  float* psec = (float*)(ws + OFF_PSEC);
  int* pidx = (int*)(ws + OFF_PIDX);
  int* counter = (int*)(ws + OFF_CNT);
  int* list = (int*)(ws + OFF_LIST);
  double* cn64 = (double*)(ws + OFF_CN64);
  f16* xh = (f16*)(ws + OFF_XH);

  hipMemsetAsync(counter, 0, 4, stream);
  prep_c<<<448, 256, 0, stream>>>(cent, cn, cn64, cTh);
  xnorm_prepx<<<N_ROWS / 16, 256, 0, stream>>>(x, xn, xh);
  kmeans_main<<<16384, 256, 0, stream>>>(xh, cTh, cn, xn, pmin, psec, pidx);
  merge_detect<<<N_ROWS / 256, 256, 0, stream>>>(pmin, psec, pidx, (int*)d_out,
                                                 list, counter);
  exact_recheck64<<<LISTCAP / 2, 256, 0, stream>>>(x, cent, cn64, list, counter,
                                                   (int*)d_out);
}